// Round 9
// baseline (492.464 us; speedup 1.0000x reference)
//
#include <hip/hip_runtime.h>
#include <math.h>

// x: [4][4096][2048] f32, importance: [4][4096] f32, W: [2048][64] f32,
// b: [64] f32, neuron_emb: [4096][64] f32
// out: [4][5120] f32  (wC 2048 | wQ 1024 | wK 1024 (==wQ) | wV 1024)
#define D_IN   2048

typedef __bf16 bf16x8 __attribute__((ext_vector_type(8)));
typedef float  f32x4  __attribute__((ext_vector_type(4)));

#define mfma16 __builtin_amdgcn_mfma_f32_16x16x32_bf16

// ---------------------------------------------------------------------------
// K0: prep.  blocks [0,1024): normalize neuron_emb rows + split hi/lo bf16.
//            blocks [1024,1536): transpose + split W -> wt[64][2048].
//            blocks [1536,1600): zero dacc (16384 floats).
__global__ __launch_bounds__(256) void k_prep(const float* __restrict__ emb,
                                              const float* __restrict__ W,
                                              __bf16* __restrict__ e_hi,
                                              __bf16* __restrict__ e_lo,
                                              __bf16* __restrict__ wt_hi,
                                              __bf16* __restrict__ wt_lo,
                                              float* __restrict__ dacc) {
    int blk = blockIdx.x, t = threadIdx.x;
    if (blk < 1024) {
        int gid  = blk * 256 + t;
        int row  = gid >> 6;
        int lane = gid & 63;
        float v  = emb[row * 64 + lane];
        float ss = v * v;
#pragma unroll
        for (int m = 32; m >= 1; m >>= 1) ss += __shfl_xor(ss, m);
        float nv = v / sqrtf(ss);
        __bf16 hb = (__bf16)nv;
        e_hi[row * 64 + lane] = hb;
        e_lo[row * 64 + lane] = (__bf16)(nv - (float)hb);
    } else if (blk < 1536) {
        int gid = (blk - 1024) * 256 + t;   // 131072 total
        int c   = gid >> 11;
        int k   = gid & 2047;
        float v = W[k * 64 + c];
        __bf16 hb = (__bf16)v;
        wt_hi[c * 2048 + k] = hb;
        wt_lo[c * 2048 + k] = (__bf16)(v - (float)hb);
    } else {
        dacc[(blk - 1536) * 256 + t] = 0.f;
    }
}

// ---------------------------------------------------------------------------
// K1: FUSED h-GEMM + Z-pass + weighted-accumulate (dacc via atomicAdd).
// 1024 blocks x 16 rows, 512 threads (8 waves) -> 4 blocks/CU, 32 waves/CU.
// Phase H: wave w computes h-partial over K slice [w*256,(w+1)*256) with
//   16x16x32 split-bf16 MFMA (1 row-tile x 4 col-tiles), waves combine via
//   LDS atomicAdd; wave 0 adds bias, splits hi/lo, stores XOR-swizzled.
// Phase Z/ACC: per segment, 8 waves sweep 32-neuron slices (chunk=256);
//   12 MFMAs (2 indep chains) + 8 exp per chunk; TLP (8 waves/SIMD) hides
//   L2 latency -- no manual double-buffer, keeps VGPR <= 64.
__global__ __launch_bounds__(512, 8) void k_fused(
        const float* __restrict__ x,
        const __bf16* __restrict__ wt_hi, const __bf16* __restrict__ wt_lo,
        const float* __restrict__ bias,
        const __bf16* __restrict__ e_hi, const __bf16* __restrict__ e_lo,
        const float* __restrict__ imp, float* __restrict__ dacc) {
    __shared__ float  h_acc[16][66];
    __shared__ __bf16 hb_hi[16][64];   // XOR-swizzled: colgrp' = colgrp ^ (row&7)
    __shared__ __bf16 hb_lo[16][64];
    __shared__ float  zs[8][4][4];

    int t    = threadIdx.x;
    int wave = t >> 6;
    int lane = t & 63;
    int l15  = lane & 15;
    int kg   = lane >> 4;          // 0..3
    int row0 = blockIdx.x * 16;
    const f32x4 z4 = {0.f, 0.f, 0.f, 0.f};

    for (int i = t; i < 16 * 66; i += 512) ((float*)h_acc)[i] = 0.f;
    __syncthreads();

    // ---------------- Phase H: h = x @ W (this block's 16 rows) ------------
    {
        f32x4 hacc[4];
#pragma unroll
        for (int ct = 0; ct < 4; ++ct) hacc[ct] = z4;
        int kb0 = wave * 256;
        const float* xr0 = x + (size_t)(row0 + l15) * D_IN + kb0 + kg * 8;
        float4 xe0, xe1, xo0, xo1;

#define LDX(B, KS) { B##0 = *(const float4*)(xr0 + (KS) * 32); \
                     B##1 = *(const float4*)(xr0 + (KS) * 32 + 4); }
#define CVT8(DH, DL, V0, V1) { \
    float av[8] = {V0.x, V0.y, V0.z, V0.w, V1.x, V1.y, V1.z, V1.w}; \
    _Pragma("unroll") for (int j = 0; j < 8; ++j) { \
        __bf16 hb = (__bf16)av[j]; DH[j] = hb; \
        DL[j] = (__bf16)(av[j] - (float)hb); } }
#define HCOMP(B, KS) { \
    bf16x8 ah, al, bw[4]; \
    CVT8(ah, al, B##0, B##1) \
    int kb = kb0 + (KS) * 32 + kg * 8; \
    _Pragma("unroll") for (int ct = 0; ct < 4; ++ct) \
        bw[ct] = *(const bf16x8*)(wt_hi + (size_t)(ct * 16 + l15) * D_IN + kb); \
    _Pragma("unroll") for (int ct = 0; ct < 4; ++ct) \
        hacc[ct] = mfma16(ah, bw[ct], hacc[ct], 0, 0, 0); \
    _Pragma("unroll") for (int ct = 0; ct < 4; ++ct) \
        hacc[ct] = mfma16(al, bw[ct], hacc[ct], 0, 0, 0); \
    _Pragma("unroll") for (int ct = 0; ct < 4; ++ct) \
        bw[ct] = *(const bf16x8*)(wt_lo + (size_t)(ct * 16 + l15) * D_IN + kb); \
    _Pragma("unroll") for (int ct = 0; ct < 4; ++ct) \
        hacc[ct] = mfma16(ah, bw[ct], hacc[ct], 0, 0, 0); }

        LDX(xe, 0)
        LDX(xo, 1) HCOMP(xe, 0)
        LDX(xe, 2) HCOMP(xo, 1)
        LDX(xo, 3) HCOMP(xe, 2)
        LDX(xe, 4) HCOMP(xo, 3)
        LDX(xo, 5) HCOMP(xe, 4)
        LDX(xe, 6) HCOMP(xo, 5)
        LDX(xo, 7) HCOMP(xe, 6)
        HCOMP(xo, 7)
#undef LDX
#undef CVT8
#undef HCOMP

        // combine the 8 waves' K-partials (C layout: col=l15, row=kg*4+r)
#pragma unroll
        for (int ct = 0; ct < 4; ++ct)
#pragma unroll
            for (int r = 0; r < 4; ++r)
                atomicAdd(&h_acc[kg * 4 + r][ct * 16 + l15], hacc[ct][r]);
    }
    __syncthreads();
    if (wave == 0) {
#pragma unroll 4
        for (int row = 0; row < 16; ++row) {
            float v = h_acc[row][lane] + bias[lane];
            __bf16 hb = (__bf16)v;
            int c2 = ((((lane >> 3) ^ (row & 7)) << 3) | (lane & 7));
            hb_hi[row][c2] = hb;
            hb_lo[row][c2] = (__bf16)(v - (float)hb);
        }
    }
    __syncthreads();

    // ---------------- A fragments from swizzled LDS ------------------------
    bf16x8 a_hi[2], a_lo[2];
#pragma unroll
    for (int ks = 0; ks < 2; ++ks) {
        int g = ((ks * 4 + kg) ^ (l15 & 7)) * 8;
        a_hi[ks] = *(const bf16x8*)&hb_hi[l15][g];
        a_lo[ks] = *(const bf16x8*)&hb_lo[l15][g];
    }

    int bb = blockIdx.x >> 8;            // batch (256 blocks per batch)
    float* dbase = dacc + bb * 4096;

    // 6 MFMAs for 16 neurons at NN into ACC (two k-slices, 3 split combos)
#define DOT16(ACC, NN) { \
    const __bf16* eh = e_hi + (size_t)((NN) + l15) * 64 + kg * 8; \
    const __bf16* el = e_lo + (size_t)((NN) + l15) * 64 + kg * 8; \
    bf16x8 h0 = *(const bf16x8*)eh; \
    bf16x8 h1 = *(const bf16x8*)(eh + 32); \
    bf16x8 l0 = *(const bf16x8*)el; \
    bf16x8 l1 = *(const bf16x8*)(el + 32); \
    ACC = mfma16(a_hi[0], h0, ACC, 0, 0, 0); \
    ACC = mfma16(a_hi[1], h1, ACC, 0, 0, 0); \
    ACC = mfma16(a_lo[0], h0, ACC, 0, 0, 0); \
    ACC = mfma16(a_lo[1], h1, ACC, 0, 0, 0); \
    ACC = mfma16(a_hi[0], l0, ACC, 0, 0, 0); \
    ACC = mfma16(a_hi[1], l1, ACC, 0, 0, 0); }

    // ---------------- Phase Z / ACC per segment ----------------------------
    const int segB[4] = {0, 2048, 3072, 4096};
    for (int sg = 0; sg < 3; ++sg) {
        int sBeg = segB[sg];
        int nc   = (segB[sg + 1] - sBeg) >> 8;   // chunks of 256 neurons
        // ---- pass A: Z ----
        float zc[4] = {};
#pragma unroll 2
        for (int c = 0; c < nc; ++c) {
            int n0 = sBeg + c * 256 + wave * 32;
            f32x4 acc0 = z4, acc1 = z4;
            DOT16(acc0, n0)
            DOT16(acc1, n0 + 16)
#pragma unroll
            for (int r = 0; r < 4; ++r)
                zc[r] += __expf(acc0[r]) + __expf(acc1[r]);
        }
        // reduce over the 16 l15-lanes (neurons), then across 8 waves
#pragma unroll
        for (int r = 0; r < 4; ++r) {
            float z = zc[r];
#pragma unroll
            for (int m = 1; m < 16; m <<= 1) z += __shfl_xor(z, m);
            zc[r] = z;
        }
        if (l15 == 0) {
#pragma unroll
            for (int r = 0; r < 4; ++r) zs[wave][kg][r] = zc[r];
        }
        __syncthreads();
        float cf[4];
#pragma unroll
        for (int r = 0; r < 4; ++r) {
            float z = 0.f;
#pragma unroll
            for (int w = 0; w < 8; ++w) z += zs[w][kg][r];
            cf[r] = imp[row0 + kg * 4 + r] / z;
        }
        __syncthreads();  // zs reused next segment
        // ---- pass B: accumulate coef*exp(l) -> atomicAdd dacc ----
#pragma unroll 2
        for (int c = 0; c < nc; ++c) {
            int n0 = sBeg + c * 256 + wave * 32;
            f32x4 acc0 = z4, acc1 = z4;
            DOT16(acc0, n0)
            DOT16(acc1, n0 + 16)
            float s0 = 0.f, s1 = 0.f;
#pragma unroll
            for (int r = 0; r < 4; ++r) {
                s0 += cf[r] * __expf(acc0[r]);
                s1 += cf[r] * __expf(acc1[r]);
            }
            // sum the 4 kg row-groups (lane bits 4,5)
            s0 += __shfl_xor(s0, 16); s0 += __shfl_xor(s0, 32);
            s1 += __shfl_xor(s1, 16); s1 += __shfl_xor(s1, 32);
            if (kg == 0) {
                atomicAdd(&dbase[n0 + l15],      s0);
                atomicAdd(&dbase[n0 + 16 + l15], s1);
            }
        }
    }
#undef DOT16
}

// ---------------------------------------------------------------------------
// K2: top-k sparsify; one block per (batch, segment) -> 12 blocks.
__global__ __launch_bounds__(256) void k_topk(const float* __restrict__ dacc,
                                              float* __restrict__ out) {
    __shared__ float dv[2048];
    __shared__ float redv[4];
    __shared__ int   redi[4];
    __shared__ float selv[8];
    __shared__ int   seli[8];
    int blk = blockIdx.x;
    int b   = blk / 3;
    int sg  = blk - 3 * b;
    int t   = threadIdx.x;
    const int segStart[3] = {0, 2048, 3072};
    const int segLen[3]   = {2048, 1024, 1024};
    const int segK[3]     = {8, 4, 6};
    const int segOut[3]   = {0, 2048, 4096};
    int st = segStart[sg], len = segLen[sg], kk = segK[sg];
    for (int n = t; n < len; n += 256) dv[n] = dacc[b * 4096 + st + n];
    __syncthreads();
    for (int it = 0; it < kk; ++it) {
        float bv = -3.0e38f;
        int   bi = 1 << 30;
        for (int n = t; n < len; n += 256) {
            float v = dv[n];
            if (v > bv) { bv = v; bi = n; }  // strict > keeps lowest idx
        }
#pragma unroll
        for (int m = 1; m < 64; m <<= 1) {
            float ov = __shfl_xor(bv, m);
            int   oi = __shfl_xor(bi, m);
            if (ov > bv || (ov == bv && oi < bi)) { bv = ov; bi = oi; }
        }
        if ((t & 63) == 0) { redv[t >> 6] = bv; redi[t >> 6] = bi; }
        __syncthreads();
        if (t == 0) {
            for (int w = 1; w < 4; ++w)
                if (redv[w] > bv || (redv[w] == bv && redi[w] < bi)) {
                    bv = redv[w]; bi = redi[w];
                }
            selv[it] = bv;
            seli[it] = bi;
            dv[bi] = -3.4e38f;
        }
        __syncthreads();
    }
    float sum = 0.f;
    for (int it = 0; it < kk; ++it) sum += selv[it];
    float inv = 1.0f / (sum + 1e-8f);
    for (int n = t; n < len; n += 256) {
        float v = 0.0f;
        for (int it = 0; it < kk; ++it)
            if (seli[it] == n) v = selv[it] * inv;
        out[b * 5120 + segOut[sg] + n] = v;
        if (sg == 1) out[b * 5120 + 3072 + n] = v;  // wK == wQ
    }
}

// ---------------------------------------------------------------------------
extern "C" void kernel_launch(void* const* d_in, const int* in_sizes, int n_in,
                              void* d_out, int out_size, void* d_ws, size_t ws_size,
                              hipStream_t stream) {
    (void)in_sizes; (void)n_in; (void)out_size; (void)ws_size;
    const float* x    = (const float*)d_in[0];
    const float* imp  = (const float*)d_in[1];
    const float* W    = (const float*)d_in[2];
    const float* bias = (const float*)d_in[3];
    const float* emb  = (const float*)d_in[4];
    float* out = (float*)d_out;

    // workspace layout (bytes): ~1.6 MB
    char* w = (char*)d_ws;
    __bf16* e_hi  = (__bf16*)w;  w += (size_t)4096 * 64 * 2;   // 512KB
    __bf16* e_lo  = (__bf16*)w;  w += (size_t)4096 * 64 * 2;   // 512KB
    __bf16* wt_hi = (__bf16*)w;  w += (size_t)64 * 2048 * 2;   // 256KB
    __bf16* wt_lo = (__bf16*)w;  w += (size_t)64 * 2048 * 2;   // 256KB
    float*  dacc  = (float*)w;   w += (size_t)4 * 4096 * 4;    // 64KB

    hipLaunchKernelGGL(k_prep,  dim3(1600), dim3(256), 0, stream,
                       emb, W, e_hi, e_lo, wt_hi, wt_lo, dacc);
    hipLaunchKernelGGL(k_fused, dim3(1024), dim3(512), 0, stream,
                       x, wt_hi, wt_lo, bias, e_hi, e_lo, imp, dacc);
    hipLaunchKernelGGL(k_topk,  dim3(12),   dim3(256), 0, stream,
                       dacc, out);
}

// Round 11
// 446.840 us; speedup vs baseline: 1.1021x; 1.1021x over previous
//
#include <hip/hip_runtime.h>
#include <math.h>

// x: [4][4096][2048] f32, importance: [4][4096] f32, W: [2048][64] f32,
// b: [64] f32, neuron_emb: [4096][64] f32
// out: [4][5120] f32  (wC 2048 | wQ 1024 | wK 1024 (==wQ) | wV 1024)
#define D_IN   2048

typedef __bf16 bf16x8 __attribute__((ext_vector_type(8)));
typedef __bf16 bf16x4 __attribute__((ext_vector_type(4)));
typedef float  f32x4  __attribute__((ext_vector_type(4)));

#define mfma16 __builtin_amdgcn_mfma_f32_16x16x32_bf16

// ---------------------------------------------------------------------------
// K0: prep.  blocks [0,1024): normalize neuron_emb rows + split hi/lo bf16.
//            blocks [1024,1536): transpose + split W -> wt[64][2048].
//            blocks [1536,1600): zero dacc (16384 floats).
__global__ __launch_bounds__(256) void k_prep(const float* __restrict__ emb,
                                              const float* __restrict__ W,
                                              __bf16* __restrict__ e_hi,
                                              __bf16* __restrict__ e_lo,
                                              __bf16* __restrict__ wt_hi,
                                              __bf16* __restrict__ wt_lo,
                                              float* __restrict__ dacc) {
    int blk = blockIdx.x, t = threadIdx.x;
    if (blk < 1024) {
        int gid  = blk * 256 + t;
        int row  = gid >> 6;
        int lane = gid & 63;
        float v  = emb[row * 64 + lane];
        float ss = v * v;
#pragma unroll
        for (int m = 32; m >= 1; m >>= 1) ss += __shfl_xor(ss, m);
        float nv = v / sqrtf(ss);
        __bf16 hb = (__bf16)nv;
        e_hi[row * 64 + lane] = hb;
        e_lo[row * 64 + lane] = (__bf16)(nv - (float)hb);
    } else if (blk < 1536) {
        int gid = (blk - 1024) * 256 + t;   // 131072 total
        int c   = gid >> 11;
        int k   = gid & 2047;
        float v = W[k * 64 + c];
        __bf16 hb = (__bf16)v;
        wt_hi[c * 2048 + k] = hb;
        wt_lo[c * 2048 + k] = (__bf16)(v - (float)hb);
    } else {
        dacc[(blk - 1536) * 256 + t] = 0.f;
    }
}

// ---------------------------------------------------------------------------
// K1: FUSED h-GEMM + single-MFMA-sweep softmax-accumulate.
// 1024 blocks x 16 rows, 512 threads (8 waves), 2 blocks/CU (75KB LDS).
// Phase H: wave w computes h-partial over K slice [w*256,(w+1)*256); waves
//   combine via LDS atomicAdd; wave 0 adds bias, splits hi/lo, XOR-swizzled.
// Phase A (per segment): ONE MFMA sweep computes logits; exp() stored as
//   bf16 in LDS [16][2064-padded]; f32 Z accumulated per row.
// Phase B: pure LDS reduction  dacc[n] += sum_row coef[row]*exp_lds[row][n]
//   (bf16x4 vector reads, 4 atomicAdds/thread) — no MFMA recompute, no
//   second e_hi/e_lo L2 sweep.
#define ESTRIDE 2064   // bf16 elements per row (2048 + 16 pad)
__global__ __launch_bounds__(512, 4) void k_fused(
        const float* __restrict__ x,
        const __bf16* __restrict__ wt_hi, const __bf16* __restrict__ wt_lo,
        const float* __restrict__ bias,
        const __bf16* __restrict__ e_hi, const __bf16* __restrict__ e_lo,
        const float* __restrict__ imp, float* __restrict__ dacc) {
    __shared__ float  h_acc[16][66];
    __shared__ __bf16 hb_hi[16][64];   // XOR-swizzled: colgrp' = colgrp ^ (row&7)
    __shared__ __bf16 hb_lo[16][64];
    __shared__ float  zs[8][4][4];
    __shared__ float  coef_lds[16];
    __shared__ __bf16 exp_lds[16 * ESTRIDE];   // 66 KB

    int t    = threadIdx.x;
    int wave = t >> 6;
    int lane = t & 63;
    int l15  = lane & 15;
    int kg   = lane >> 4;          // 0..3
    int row0 = blockIdx.x * 16;
    const f32x4 z4 = {0.f, 0.f, 0.f, 0.f};

    for (int i = t; i < 16 * 66; i += 512) ((float*)h_acc)[i] = 0.f;
    __syncthreads();

    // ---------------- Phase H: h = x @ W (this block's 16 rows) ------------
    {
        f32x4 hacc[4];
#pragma unroll
        for (int ct = 0; ct < 4; ++ct) hacc[ct] = z4;
        int kb0 = wave * 256;
        const float* xr0 = x + (size_t)(row0 + l15) * D_IN + kb0 + kg * 8;
        float4 xe0, xe1, xo0, xo1;

#define LDX(B, KS) { B##0 = *(const float4*)(xr0 + (KS) * 32); \
                     B##1 = *(const float4*)(xr0 + (KS) * 32 + 4); }
#define CVT8(DH, DL, V0, V1) { \
    float av[8] = {V0.x, V0.y, V0.z, V0.w, V1.x, V1.y, V1.z, V1.w}; \
    _Pragma("unroll") for (int j = 0; j < 8; ++j) { \
        __bf16 hb = (__bf16)av[j]; DH[j] = hb; \
        DL[j] = (__bf16)(av[j] - (float)hb); } }
#define HCOMP(B, KS) { \
    bf16x8 ah, al, bw[4]; \
    CVT8(ah, al, B##0, B##1) \
    int kb = kb0 + (KS) * 32 + kg * 8; \
    _Pragma("unroll") for (int ct = 0; ct < 4; ++ct) \
        bw[ct] = *(const bf16x8*)(wt_hi + (size_t)(ct * 16 + l15) * D_IN + kb); \
    _Pragma("unroll") for (int ct = 0; ct < 4; ++ct) \
        hacc[ct] = mfma16(ah, bw[ct], hacc[ct], 0, 0, 0); \
    _Pragma("unroll") for (int ct = 0; ct < 4; ++ct) \
        hacc[ct] = mfma16(al, bw[ct], hacc[ct], 0, 0, 0); \
    _Pragma("unroll") for (int ct = 0; ct < 4; ++ct) \
        bw[ct] = *(const bf16x8*)(wt_lo + (size_t)(ct * 16 + l15) * D_IN + kb); \
    _Pragma("unroll") for (int ct = 0; ct < 4; ++ct) \
        hacc[ct] = mfma16(ah, bw[ct], hacc[ct], 0, 0, 0); }

        LDX(xe, 0)
        LDX(xo, 1) HCOMP(xe, 0)
        LDX(xe, 2) HCOMP(xo, 1)
        LDX(xo, 3) HCOMP(xe, 2)
        LDX(xe, 4) HCOMP(xo, 3)
        LDX(xo, 5) HCOMP(xe, 4)
        LDX(xe, 6) HCOMP(xo, 5)
        LDX(xo, 7) HCOMP(xe, 6)
        HCOMP(xo, 7)
#undef LDX
#undef CVT8
#undef HCOMP

        // combine the 8 waves' K-partials (C layout: col=l15, row=kg*4+r)
#pragma unroll
        for (int ct = 0; ct < 4; ++ct)
#pragma unroll
            for (int r = 0; r < 4; ++r)
                atomicAdd(&h_acc[kg * 4 + r][ct * 16 + l15], hacc[ct][r]);
    }
    __syncthreads();
    if (wave == 0) {
#pragma unroll 4
        for (int row = 0; row < 16; ++row) {
            float v = h_acc[row][lane] + bias[lane];
            __bf16 hb = (__bf16)v;
            int c2 = ((((lane >> 3) ^ (row & 7)) << 3) | (lane & 7));
            hb_hi[row][c2] = hb;
            hb_lo[row][c2] = (__bf16)(v - (float)hb);
        }
    }
    __syncthreads();

    // ---------------- A fragments from swizzled LDS ------------------------
    bf16x8 a_hi[2], a_lo[2];
#pragma unroll
    for (int ks = 0; ks < 2; ++ks) {
        int g = ((ks * 4 + kg) ^ (l15 & 7)) * 8;
        a_hi[ks] = *(const bf16x8*)&hb_hi[l15][g];
        a_lo[ks] = *(const bf16x8*)&hb_lo[l15][g];
    }

    int bb = blockIdx.x >> 8;            // batch (256 blocks per batch)
    float* dbase = dacc + bb * 4096;

    // 6 MFMAs for 16 neurons at NN into ACC (two k-slices, 3 split combos)
#define DOT16(ACC, NN) { \
    const __bf16* eh = e_hi + (size_t)((NN) + l15) * 64 + kg * 8; \
    const __bf16* el = e_lo + (size_t)((NN) + l15) * 64 + kg * 8; \
    bf16x8 h0 = *(const bf16x8*)eh; \
    bf16x8 h1 = *(const bf16x8*)(eh + 32); \
    bf16x8 l0 = *(const bf16x8*)el; \
    bf16x8 l1 = *(const bf16x8*)(el + 32); \
    ACC = mfma16(a_hi[0], h0, ACC, 0, 0, 0); \
    ACC = mfma16(a_hi[1], h1, ACC, 0, 0, 0); \
    ACC = mfma16(a_lo[0], h0, ACC, 0, 0, 0); \
    ACC = mfma16(a_lo[1], h1, ACC, 0, 0, 0); \
    ACC = mfma16(a_hi[0], l0, ACC, 0, 0, 0); \
    ACC = mfma16(a_hi[1], l1, ACC, 0, 0, 0); }

    // ---------------- Per segment: one MFMA sweep + LDS reduce -------------
    const int segB[4]   = {0, 2048, 3072, 4096};
    const int segLen3[3] = {2048, 1024, 1024};
    for (int sg = 0; sg < 3; ++sg) {
        int sBeg = segB[sg];
        int L    = segLen3[sg];
        int nc   = L >> 8;                 // chunks of 256 neurons
        // ---- pass A: logits -> exp (f32 for Z, bf16 store) ----
        float zc[4] = {};
        for (int c = 0; c < nc; ++c) {
            int noff = c * 256 + wave * 32;        // offset within segment
            f32x4 acc0 = z4, acc1 = z4;
            DOT16(acc0, sBeg + noff)
            DOT16(acc1, sBeg + noff + 16)
#pragma unroll
            for (int r = 0; r < 4; ++r) {
                float e0 = __expf(acc0[r]);
                float e1 = __expf(acc1[r]);
                zc[r] += e0 + e1;
                int rr = kg * 4 + r;
                exp_lds[rr * ESTRIDE + noff + l15]      = (__bf16)e0;
                exp_lds[rr * ESTRIDE + noff + 16 + l15] = (__bf16)e1;
            }
        }
        // reduce Z over the 16 l15-lanes, publish per-wave partials
#pragma unroll
        for (int r = 0; r < 4; ++r) {
            float z = zc[r];
#pragma unroll
            for (int m = 1; m < 16; m <<= 1) z += __shfl_xor(z, m);
            zc[r] = z;
        }
        if (l15 == 0) {
#pragma unroll
            for (int r = 0; r < 4; ++r) zs[wave][kg][r] = zc[r];
        }
        __syncthreads();
        if (wave == 0 && l15 == 0) {
#pragma unroll
            for (int r = 0; r < 4; ++r) {
                float z = 0.f;
#pragma unroll
                for (int w = 0; w < 8; ++w) z += zs[w][kg][r];
                coef_lds[kg * 4 + r] = imp[row0 + kg * 4 + r] / z;
            }
        }
        __syncthreads();
        // ---- pass B: dacc[n] += sum_row coef[row] * exp_lds[row][n] ----
        int n4 = t * 4;
        if (n4 < L) {
            float s[4] = {0.f, 0.f, 0.f, 0.f};
#pragma unroll
            for (int row = 0; row < 16; ++row) {
                bf16x4 ev = *(const bf16x4*)&exp_lds[row * ESTRIDE + n4];
                float c = coef_lds[row];
#pragma unroll
                for (int j = 0; j < 4; ++j) s[j] += c * (float)ev[j];
            }
#pragma unroll
            for (int j = 0; j < 4; ++j)
                atomicAdd(&dbase[sBeg + n4 + j], s[j]);
        }
        __syncthreads();   // exp_lds reused by next segment's pass A
    }
#undef DOT16
}

// ---------------------------------------------------------------------------
// K2: top-k sparsify; one block per (batch, segment) -> 12 blocks.
__global__ __launch_bounds__(256) void k_topk(const float* __restrict__ dacc,
                                              float* __restrict__ out) {
    __shared__ float dv[2048];
    __shared__ float redv[4];
    __shared__ int   redi[4];
    __shared__ float selv[8];
    __shared__ int   seli[8];
    int blk = blockIdx.x;
    int b   = blk / 3;
    int sg  = blk - 3 * b;
    int t   = threadIdx.x;
    const int segStart[3] = {0, 2048, 3072};
    const int segLen[3]   = {2048, 1024, 1024};
    const int segK[3]     = {8, 4, 6};
    const int segOut[3]   = {0, 2048, 4096};
    int st = segStart[sg], len = segLen[sg], kk = segK[sg];
    for (int n = t; n < len; n += 256) dv[n] = dacc[b * 4096 + st + n];
    __syncthreads();
    for (int it = 0; it < kk; ++it) {
        float bv = -3.0e38f;
        int   bi = 1 << 30;
        for (int n = t; n < len; n += 256) {
            float v = dv[n];
            if (v > bv) { bv = v; bi = n; }  // strict > keeps lowest idx
        }
#pragma unroll
        for (int m = 1; m < 64; m <<= 1) {
            float ov = __shfl_xor(bv, m);
            int   oi = __shfl_xor(bi, m);
            if (ov > bv || (ov == bv && oi < bi)) { bv = ov; bi = oi; }
        }
        if ((t & 63) == 0) { redv[t >> 6] = bv; redi[t >> 6] = bi; }
        __syncthreads();
        if (t == 0) {
            for (int w = 1; w < 4; ++w)
                if (redv[w] > bv || (redv[w] == bv && redi[w] < bi)) {
                    bv = redv[w]; bi = redi[w];
                }
            selv[it] = bv;
            seli[it] = bi;
            dv[bi] = -3.4e38f;
        }
        __syncthreads();
    }
    float sum = 0.f;
    for (int it = 0; it < kk; ++it) sum += selv[it];
    float inv = 1.0f / (sum + 1e-8f);
    for (int n = t; n < len; n += 256) {
        float v = 0.0f;
        for (int it = 0; it < kk; ++it)
            if (seli[it] == n) v = selv[it] * inv;
        out[b * 5120 + segOut[sg] + n] = v;
        if (sg == 1) out[b * 5120 + 3072 + n] = v;  // wK == wQ
    }
}

// ---------------------------------------------------------------------------
extern "C" void kernel_launch(void* const* d_in, const int* in_sizes, int n_in,
                              void* d_out, int out_size, void* d_ws, size_t ws_size,
                              hipStream_t stream) {
    (void)in_sizes; (void)n_in; (void)out_size; (void)ws_size;
    const float* x    = (const float*)d_in[0];
    const float* imp  = (const float*)d_in[1];
    const float* W    = (const float*)d_in[2];
    const float* bias = (const float*)d_in[3];
    const float* emb  = (const float*)d_in[4];
    float* out = (float*)d_out;

    // workspace layout (bytes): ~1.6 MB
    char* w = (char*)d_ws;
    __bf16* e_hi  = (__bf16*)w;  w += (size_t)4096 * 64 * 2;   // 512KB
    __bf16* e_lo  = (__bf16*)w;  w += (size_t)4096 * 64 * 2;   // 512KB
    __bf16* wt_hi = (__bf16*)w;  w += (size_t)64 * 2048 * 2;   // 256KB
    __bf16* wt_lo = (__bf16*)w;  w += (size_t)64 * 2048 * 2;   // 256KB
    float*  dacc  = (float*)w;   w += (size_t)4 * 4096 * 4;    // 64KB

    hipLaunchKernelGGL(k_prep,  dim3(1600), dim3(256), 0, stream,
                       emb, W, e_hi, e_lo, wt_hi, wt_lo, dacc);
    hipLaunchKernelGGL(k_fused, dim3(1024), dim3(512), 0, stream,
                       x, wt_hi, wt_lo, bias, e_hi, e_lo, imp, dacc);
    hipLaunchKernelGGL(k_topk,  dim3(12),   dim3(256), 0, stream,
                       dacc, out);
}